// Round 27
// baseline (304.717 us; speedup 1.0000x reference)
//
#include <hip/hip_runtime.h>

#define TT 8192          // B*S tokens
#define DD 1024          // model dim
#define HHH 2048         // hidden dim
#define EE 8             // experts
#define MUf 0.7f
#define GAMMAf 1.0f
#define LNEPS 1e-5f

typedef __bf16 bf16x8 __attribute__((ext_vector_type(8)));
typedef float floatx4 __attribute__((ext_vector_type(4)));

__device__ __forceinline__ unsigned short f2bf(float f) {
  unsigned u = __float_as_uint(f);
  u += 0x7FFFu + ((u >> 16) & 1u);          // round-to-nearest-even
  return (unsigned short)(u >> 16);
}
__device__ __forceinline__ float bf2f(unsigned short u) {
  return __uint_as_float(((unsigned)u) << 16);
}
__device__ __forceinline__ void load_lds16(const void* g, void* l) {
  __builtin_amdgcn_global_load_lds(
      (__attribute__((address_space(1))) void*)g,
      (__attribute__((address_space(3))) void*)l,
      16, 0, 0);
}

// ------- fused x->bf16 convert + router (each block = exactly 2 token rows) -------
__global__ __launch_bounds__(256) void cvt_router_kernel(
    const float* __restrict__ x, const float* __restrict__ Wg, const float* __restrict__ bg,
    unsigned short* __restrict__ xb,
    int* __restrict__ pair_e, float* __restrict__ pair_w) {
  int tid = threadIdx.x;
  size_t gi = (size_t)blockIdx.x * 2048 + (size_t)tid * 8;
  const float4* s = (const float4*)(x + gi);
  float4 a = s[0], b = s[1];
  unsigned r0 = f2bf(a.x) | ((unsigned)f2bf(a.y) << 16);
  unsigned r1 = f2bf(a.z) | ((unsigned)f2bf(a.w) << 16);
  unsigned r2 = f2bf(b.x) | ((unsigned)f2bf(b.y) << 16);
  unsigned r3 = f2bf(b.z) | ((unsigned)f2bf(b.w) << 16);
  ((uint4*)xb)[blockIdx.x * 256 + tid] = make_uint4(r0, r1, r2, r3);

  float xa[8] = {a.x, a.y, a.z, a.w, b.x, b.y, b.z, b.w};
  int d0 = (tid & 127) * 8;
  const float* wbase = Wg + (size_t)d0 * EE;
  float acc[EE];
#pragma unroll
  for (int e = 0; e < EE; ++e) acc[e] = 0.f;
#pragma unroll
  for (int i = 0; i < 8; ++i) {
    float4 w0 = *(const float4*)(wbase + i * EE);
    float4 w1 = *(const float4*)(wbase + i * EE + 4);
    acc[0] += xa[i] * w0.x; acc[1] += xa[i] * w0.y;
    acc[2] += xa[i] * w0.z; acc[3] += xa[i] * w0.w;
    acc[4] += xa[i] * w1.x; acc[5] += xa[i] * w1.y;
    acc[6] += xa[i] * w1.z; acc[7] += xa[i] * w1.w;
  }
#pragma unroll
  for (int e = 0; e < EE; ++e) {
#pragma unroll
    for (int off = 32; off > 0; off >>= 1) acc[e] += __shfl_xor(acc[e], off);
  }
  __shared__ float rs[4][EE];
  int wv = tid >> 6;
  if ((tid & 63) == 0) {
#pragma unroll
    for (int e = 0; e < EE; ++e) rs[wv][e] = acc[e];
  }
  __syncthreads();
  if ((tid & 127) == 0) {
    int half = tid >> 7;
    int t = blockIdx.x * 2 + half;
    float v[EE];
#pragma unroll
    for (int e = 0; e < EE; ++e) v[e] = rs[2 * half][e] + rs[2 * half + 1][e] + bg[e];
    int i0 = 0;
#pragma unroll
    for (int e = 1; e < EE; ++e) if (v[e] > v[i0]) i0 = e;      // ties -> lowest idx
    int i1 = (i0 == 0) ? 1 : 0;
#pragma unroll
    for (int e = 0; e < EE; ++e) if (e != i0 && v[e] > v[i1]) i1 = e;
    float w1e = __expf(v[i1] - v[i0]);
    float inv = 1.f / (1.f + w1e);
    pair_e[2 * t] = i0;     pair_w[2 * t] = inv;
    pair_e[2 * t + 1] = i1; pair_w[2 * t + 1] = w1e * inv;
  }
}

// ------- fused LDS-histogram count + last-block prefix -------
// counts[0..7] histogram; counts[8] = done counter (all memset to 0 each call).
__global__ __launch_bounds__(256) void count_prefix_kernel(
    const int* __restrict__ pair_e, int* __restrict__ counts,
    int* __restrict__ offs, int* __restrict__ cursor) {
  __shared__ int lh[EE];
  int tid = threadIdx.x;
  if (tid < EE) lh[tid] = 0;
  __syncthreads();
  int p = blockIdx.x * 256 + tid;
  atomicAdd(&lh[pair_e[p]], 1);
  __syncthreads();
  if (tid < EE) atomicAdd(&counts[tid], lh[tid]);
  __threadfence();                           // counts visible before done bump
  __syncthreads();
  if (tid == 0) {
    int old = atomicAdd(&counts[EE], 1);
    if (old == gridDim.x - 1) {              // last block: all counts landed
      __threadfence();
      int s = 0;
      for (int e = 0; e < EE; ++e) { offs[e] = s; cursor[e] = s; s += counts[e]; }
      offs[EE] = s;
    }
  }
}

// ------- chunk-reserving scatter -------
__global__ __launch_bounds__(256) void scatter_kernel(const int* __restrict__ pair_e,
                                                      int* __restrict__ cursor,
                                                      int* __restrict__ pair_rows) {
  __shared__ int lh[EE];
  __shared__ int lb[EE];
  int tid = threadIdx.x;
  if (tid < EE) lh[tid] = 0;
  __syncthreads();
  int p = blockIdx.x * 256 + tid;
  int e = pair_e[p];
  int r = atomicAdd(&lh[e], 1);
  __syncthreads();
  if (tid < EE) lb[tid] = atomicAdd(&cursor[tid], lh[tid]);
  __syncthreads();
  pair_rows[lb[e] + r] = p;
}

// ---- merged W1+W2 transpose+cvt, 64x64 tiles, float4 loads / ushort4 stores ----
__global__ __launch_bounds__(256) void transpose_cvt_kernel(
    const float* __restrict__ w1, unsigned short* __restrict__ o1,
    const float* __restrict__ w2, unsigned short* __restrict__ o2) {
  __shared__ float tile[64][65];
  int bid = blockIdx.x;
  int half = bid >> 12;                 // 0: W1, 1: W2
  int e = (bid >> 9) & 7;
  int tl = bid & 511;
  int R, C, tx, ty;
  const float* src;
  unsigned short* dst;
  if (half == 0) {
    R = DD; C = HHH; tx = tl & 31; ty = tl >> 5;      // 32 x 16
    src = w1 + (size_t)e * R * C; dst = o1 + (size_t)e * R * C;
  } else {
    R = HHH; C = DD; tx = tl & 15; ty = tl >> 4;      // 16 x 32
    src = w2 + (size_t)e * R * C; dst = o2 + (size_t)e * R * C;
  }
  int c0 = tx * 64, r0 = ty * 64;
  int t = threadIdx.x;
  int q = t & 15, r = t >> 4;
#pragma unroll
  for (int i = 0; i < 4; ++i) {
    int rr = r + 16 * i;
    float4 v = *(const float4*)(src + (size_t)(r0 + rr) * C + c0 + q * 4);
    tile[rr][q * 4 + 0] = v.x; tile[rr][q * 4 + 1] = v.y;
    tile[rr][q * 4 + 2] = v.z; tile[rr][q * 4 + 3] = v.w;
  }
  __syncthreads();
  int g = t & 15, cc = t >> 4;
#pragma unroll
  for (int i = 0; i < 4; ++i) {
    int c = cc + 16 * i;
    ushort4 o;
    o.x = f2bf(tile[g * 4 + 0][c]);
    o.y = f2bf(tile[g * 4 + 1][c]);
    o.z = f2bf(tile[g * 4 + 2][c]);
    o.w = f2bf(tile[g * 4 + 3][c]);
    *(ushort4*)(dst + (size_t)(c0 + c) * R + r0 + g * 4) = o;
  }
}

// --- grouped GEMM, 128x128 tile, BK=32, 3-slab ring, PAIR-structured + COUNTED vmcnt ---
// Per pair P (tiles kt=2P, kt+1): vmcnt(4) [outstanding 8: kt,kt+1; oldest 4 = kt landed,
// kt+1 stays in flight across barrier A] -> barrier A -> read+MFMA tile kt (slab s0) ->
// barrier B -> sched_barrier -> batched stage tiles kt+2 (slab tg0) and kt+3 (slab s0)
// [outstanding 12] -> vmcnt(8) [oldest 4 = kt+1 landed] -> read+MFMA tile kt+1 (slab sB).
// Last pair: no stages; vmcnt(0) before readB. WAR as round-24 (stage targets s0, read
// before barrier B this pair; tg0 = prev pair's sB, read two barriers ago).
// Grid-stride m-tiles (32 slots); expert->XCD pinning (d&7).
// MODE 0: A = xb gathered via pair_rows, epilogue relu -> h[sorted_pos]
// MODE 1: A = h (sorted rows direct),    epilogue gate-scale -> pairout[pair]
template <int MODE>
__global__ __launch_bounds__(256, 3) void moe_gemm_kernel(
    const unsigned short* __restrict__ Amat, const unsigned short* __restrict__ Bmat,
    const float* __restrict__ bias, const int* __restrict__ offsets,
    const int* __restrict__ pair_rows, const float* __restrict__ pair_w,
    unsigned short* __restrict__ Out, int Kd, int Nd, int nxlog) {
  int d = blockIdx.x;
  int e = d & 7;                               // expert == XCD (round-robin %8)
  int lin = d >> 3;
  int mt0 = lin >> nxlog;                      // starting m-tile slot [0,32)
  int n0 = (lin & ((1 << nxlog) - 1)) << 7;    // n-tile * 128
  int off = offsets[e];
  int cnt = offsets[e + 1] - off;
  int tid = threadIdx.x;
  int lane = tid & 63, wid = tid >> 6;

  __shared__ unsigned short As[3][128 * 32];   // 3 x 8 KB
  __shared__ unsigned short Bs[3][128 * 32];   // 3 x 8 KB  (48 KB total -> 3 blocks/CU)

  const unsigned short* Bex = Bmat + (size_t)e * Nd * Kd;
  int csw = (((tid & 3) ^ ((tid >> 2) & 3)) * 8);
  int wm = (wid >> 1) * 64, wn = (wid & 1) * 64;
  int lr = lane & 15;
  int t4 = lane >> 4;
  int lka = ((t4 ^ (lr & 3)) * 8);
  int NT = Kd >> 5;                            // even (32 or 64)

  for (int mt = mt0; mt * 128 < cnt; mt += 32) {
    __syncthreads();                          // prior mt's slot readers done

    const unsigned short* aptr[2];
    const unsigned short* bptr[2];
#pragma unroll
    for (int P = 0; P < 2; ++P) {
      int row = P * 64 + (tid >> 2);
      int sa = mt * 128 + row;
      if (sa >= cnt) sa = cnt - 1;            // clamp (dup loads; masked at C-write)
      int gr = (MODE == 0) ? (pair_rows[off + sa] >> 1) : (off + sa);
      aptr[P] = Amat + (size_t)gr * Kd + csw;
      bptr[P] = Bex + (size_t)(n0 + row) * Kd + csw;
    }

    floatx4 acc[4][4];
#pragma unroll
    for (int m = 0; m < 4; ++m)
#pragma unroll
      for (int n = 0; n < 4; ++n) acc[m][n] = (floatx4){0.f, 0.f, 0.f, 0.f};

    // prologue: stage K-tiles 0 and 1 into ring slots 0,1 (8 loads outstanding)
#pragma unroll
    for (int P = 0; P < 2; ++P) {
      load_lds16(aptr[P], &As[0][P * 2048] + tid * 8);
      load_lds16(bptr[P], &Bs[0][P * 2048] + tid * 8);
    }
#pragma unroll
    for (int P = 0; P < 2; ++P) {
      load_lds16(aptr[P] + 32, &As[1][P * 2048] + tid * 8);
      load_lds16(bptr[P] + 32, &Bs[1][P * 2048] + tid * 8);
    }

    int s0 = 0;                               // slab of even tile of the pair
    int NP = NT >> 1;
    for (int P = 0; P < NP; ++P) {
      int kt = 2 * P;
      int sB = s0 + 1; if (sB == 3) sB = 0;
      int tg0 = s0 + 2; if (tg0 >= 3) tg0 -= 3;
      bool more = (kt + 2) < NT;
      asm volatile("s_waitcnt vmcnt(4)" ::: "memory");  // tile kt landed; kt+1 in flight
      __builtin_amdgcn_s_barrier();                     // barrier A
      {
        bf16x8 af[4], bfr[4];
#pragma unroll
        for (int m = 0; m < 4; ++m)
          af[m] = *(const bf16x8*)(&As[s0][(wm + m * 16 + lr) * 32 + lka]);
#pragma unroll
        for (int n = 0; n < 4; ++n)
          bfr[n] = *(const bf16x8*)(&Bs[s0][(wn + n * 16 + lr) * 32 + lka]);
#pragma unroll
        for (int m = 0; m < 4; ++m)
#pragma unroll
          for (int n = 0; n < 4; ++n)
            acc[m][n] = __builtin_amdgcn_mfma_f32_16x16x32_bf16(af[m], bfr[n], acc[m][n], 0, 0, 0);
      }
      __builtin_amdgcn_s_barrier();                     // barrier B: slab reads done
      __builtin_amdgcn_sched_barrier(0);                // pin stages below barrier B
      if (more) {                                       // stage tiles kt+2, kt+3
        int ko2 = (kt + 2) * 32, ko3 = (kt + 3) * 32;
#pragma unroll
        for (int Q = 0; Q < 2; ++Q) {
          load_lds16(aptr[Q] + ko2, &As[tg0][Q * 2048] + tid * 8);
          load_lds16(bptr[Q] + ko2, &Bs[tg0][Q * 2048] + tid * 8);
        }
#pragma unroll
        for (int Q = 0; Q < 2; ++Q) {
          load_lds16(aptr[Q] + ko3, &As[s0][Q * 2048] + tid * 8);
          load_lds16(bptr[Q] + ko3, &Bs[s0][Q * 2048] + tid * 8);
        }
        asm volatile("s_waitcnt vmcnt(8)" ::: "memory"); // tile kt+1 landed (12 outstanding)
      } else {
        asm volatile("s_waitcnt vmcnt(0)" ::: "memory"); // last pair: drain
      }
      {
        bf16x8 af[4], bfr[4];                           // tile kt+1
#pragma unroll
        for (int m = 0; m < 4; ++m)
          af[m] = *(const bf16x8*)(&As[sB][(wm + m * 16 + lr) * 32 + lka]);
#pragma unroll
        for (int n = 0; n < 4; ++n)
          bfr[n] = *(const bf16x8*)(&Bs[sB][(wn + n * 16 + lr) * 32 + lka]);
#pragma unroll
        for (int m = 0; m < 4; ++m)
#pragma unroll
          for (int n = 0; n < 4; ++n)
            acc[m][n] = __builtin_amdgcn_mfma_f32_16x16x32_bf16(af[m], bfr[n], acc[m][n], 0, 0, 0);
      }
      s0 = tg0;                                         // (s0+2)%3
    }
    asm volatile("s_waitcnt vmcnt(0)" ::: "memory");    // clean load ledger for next mt

    int rem = cnt - mt * 128;
    if (rem > 128) rem = 128;
#pragma unroll
    for (int m = 0; m < 4; ++m) {
#pragma unroll
      for (int j = 0; j < 4; ++j) {
        int lrr = wm + m * 16 + ((lane >> 4) << 2) + j;   // C/D: col=lane&15, row=(lane>>4)*4+j
        if (lrr < rem) {
          int s = mt * 128 + lrr;
          size_t orow;
          float scale = 1.f;
          if (MODE == 0) {
            orow = (size_t)(off + s) * Nd;
          } else {
            int p = pair_rows[off + s];
            orow = (size_t)p * Nd;
            scale = pair_w[p];
          }
#pragma unroll
          for (int n = 0; n < 4; ++n) {
            int col = n0 + wn + n * 16 + lr;
            float v = acc[m][n][j] + bias[e * Nd + col];
            if (MODE == 0) v = fmaxf(v, 0.f);
            else v *= scale;
            Out[orow + col] = f2bf(v);
          }
        }
      }
    }
  }
}

// ---------------- fused epilogue: sum pairs, momentum, residual, LayerNorm ----------------
__global__ __launch_bounds__(256) void final_kernel(
    const float* __restrict__ x, const float* __restrict__ mom,
    const unsigned short* __restrict__ pairout, const float* __restrict__ ln_g,
    const float* __restrict__ ln_b, float* __restrict__ outp, float* __restrict__ nmp) {
  int t = blockIdx.x, tid = threadIdx.x;
  int d0 = tid * 4;
  size_t rowoff = (size_t)t * DD;
  const unsigned short* p0 = pairout + (size_t)(2 * t) * DD;
  const unsigned short* p1 = p0 + DD;
  float4 xv = *(const float4*)(x + rowoff + d0);
  float4 mv = *(const float4*)(mom + rowoff + d0);
  ushort4 u0 = *(const ushort4*)(p0 + d0);
  ushort4 u1 = *(const ushort4*)(p1 + d0);
  float eo[4] = {bf2f(u0.x) + bf2f(u1.x), bf2f(u0.y) + bf2f(u1.y),
                 bf2f(u0.z) + bf2f(u1.z), bf2f(u0.w) + bf2f(u1.w)};
  float xa[4] = {xv.x, xv.y, xv.z, xv.w};
  float ma[4] = {mv.x, mv.y, mv.z, mv.w};
  float o[4], nm[4];
  float s1 = 0.f, s2 = 0.f;
#pragma unroll
  for (int j = 0; j < 4; ++j) {
    nm[j] = MUf * ma[j] - eo[j];
    o[j] = xa[j] + GAMMAf * nm[j];
    s1 += o[j];
    s2 += o[j] * o[j];
  }
  *(float4*)(nmp + rowoff + d0) = make_float4(nm[0], nm[1], nm[2], nm[3]);
#pragma unroll
  for (int off = 32; off > 0; off >>= 1) {
    s1 += __shfl_xor(s1, off);
    s2 += __shfl_xor(s2, off);
  }
  __shared__ float rs[8];
  int wid = tid >> 6, lane = tid & 63;
  if (lane == 0) { rs[wid] = s1; rs[4 + wid] = s2; }
  __syncthreads();
  s1 = rs[0] + rs[1] + rs[2] + rs[3];
  s2 = rs[4] + rs[5] + rs[6] + rs[7];
  float mean = s1 * (1.f / DD);
  float var = s2 * (1.f / DD) - mean * mean;
  float rstd = rsqrtf(var + LNEPS);
  float4 g = *(const float4*)(ln_g + d0);
  float4 bb = *(const float4*)(ln_b + d0);
  float ga[4] = {g.x, g.y, g.z, g.w}, ba[4] = {bb.x, bb.y, bb.z, bb.w};
  float res[4];
#pragma unroll
  for (int j = 0; j < 4; ++j) res[j] = (o[j] - mean) * rstd * ga[j] + ba[j];
  *(float4*)(outp + rowoff + d0) = make_float4(res[0], res[1], res[2], res[3]);
}

extern "C" void kernel_launch(void* const* d_in, const int* in_sizes, int n_in,
                              void* d_out, int out_size, void* d_ws, size_t ws_size,
                              hipStream_t stream) {
  const float* x   = (const float*)d_in[0];
  const float* mom = (const float*)d_in[1];
  const float* Wg  = (const float*)d_in[2];
  const float* bg  = (const float*)d_in[3];
  const float* W1  = (const float*)d_in[4];
  const float* b1  = (const float*)d_in[5];
  const float* W2  = (const float*)d_in[6];
  const float* b2  = (const float*)d_in[7];
  const float* lng = (const float*)d_in[8];
  const float* lnb = (const float*)d_in[9];
  (void)in_sizes; (void)n_in; (void)out_size; (void)ws_size;
  float* outp = (float*)d_out;
  float* nmp  = outp + (size_t)TT * DD;

  char* base = (char*)d_ws;
  size_t off = 0;
  auto carve = [&](size_t bytes) {
    void* p = base + off;
    off += (bytes + 255) & ~(size_t)255;
    return p;
  };
  unsigned short* xb   = (unsigned short*)carve((size_t)TT * DD * 2);        // 16 MB
  unsigned short* w1t  = (unsigned short*)carve((size_t)EE * HHH * DD * 2);  // 32 MB  [E][H][D]
  unsigned short* w2t  = (unsigned short*)carve((size_t)EE * DD * HHH * 2);  // 32 MB  [E][D][H]
  unsigned short* hbuf = (unsigned short*)carve((size_t)2 * TT * HHH * 2);   // 64 MB
  unsigned short* pout = (unsigned short*)carve((size_t)2 * TT * DD * 2);    // 32 MB
  int*   pair_e    = (int*)carve((size_t)2 * TT * 4);
  float* pair_w    = (float*)carve((size_t)2 * TT * 4);
  int*   pair_rows = (int*)carve((size_t)2 * TT * 4);
  int*   counts    = (int*)carve(256);       // [0..7] counts, [8] done
  int*   offs      = (int*)carve(256);
  int*   cursor    = (int*)carve(256);

  hipMemsetAsync(counts, 0, (EE + 1) * sizeof(int), stream);
  cvt_router_kernel<<<TT / 2, 256, 0, stream>>>(x, Wg, bg, xb, pair_e, pair_w);
  count_prefix_kernel<<<(2 * TT) / 256, 256, 0, stream>>>(pair_e, counts, offs, cursor);
  scatter_kernel<<<(2 * TT) / 256, 256, 0, stream>>>(pair_e, cursor, pair_rows);
  transpose_cvt_kernel<<<8192, 256, 0, stream>>>(W1, w1t, W2, w2t);
  // flat grids: expert = blockIdx.x & 7; NX n-tiles x 32 m-tile start slots (grid-stride)
  moe_gemm_kernel<0><<<EE * (HHH / 128) * 32, 256, 0, stream>>>(
      xb, w1t, b1, offs, pair_rows, pair_w, hbuf, DD, HHH, 4);
  moe_gemm_kernel<1><<<EE * (DD / 128) * 32, 256, 0, stream>>>(
      hbuf, w2t, b2, offs, pair_rows, pair_w, pout, HHH, DD, 3);
  final_kernel<<<TT, 256, 0, stream>>>(x, mom, pout, lng, lnb, outp, nmp);
}

// Round 28
// 300.411 us; speedup vs baseline: 1.0143x; 1.0143x over previous
//
#include <hip/hip_runtime.h>

#define TT 8192          // B*S tokens
#define DD 1024          // model dim
#define HHH 2048         // hidden dim
#define EE 8             // experts
#define MUf 0.7f
#define GAMMAf 1.0f
#define LNEPS 1e-5f

typedef __bf16 bf16x8 __attribute__((ext_vector_type(8)));
typedef float floatx4 __attribute__((ext_vector_type(4)));

__device__ __forceinline__ unsigned short f2bf(float f) {
  unsigned u = __float_as_uint(f);
  u += 0x7FFFu + ((u >> 16) & 1u);          // round-to-nearest-even
  return (unsigned short)(u >> 16);
}
__device__ __forceinline__ float bf2f(unsigned short u) {
  return __uint_as_float(((unsigned)u) << 16);
}
__device__ __forceinline__ void load_lds16(const void* g, void* l) {
  __builtin_amdgcn_global_load_lds(
      (__attribute__((address_space(1))) void*)g,
      (__attribute__((address_space(3))) void*)l,
      16, 0, 0);
}

// ------- fused x->bf16 convert + router (each block = exactly 2 token rows) -------
__global__ __launch_bounds__(256) void cvt_router_kernel(
    const float* __restrict__ x, const float* __restrict__ Wg, const float* __restrict__ bg,
    unsigned short* __restrict__ xb,
    int* __restrict__ pair_e, float* __restrict__ pair_w) {
  int tid = threadIdx.x;
  size_t gi = (size_t)blockIdx.x * 2048 + (size_t)tid * 8;
  const float4* s = (const float4*)(x + gi);
  float4 a = s[0], b = s[1];
  unsigned r0 = f2bf(a.x) | ((unsigned)f2bf(a.y) << 16);
  unsigned r1 = f2bf(a.z) | ((unsigned)f2bf(a.w) << 16);
  unsigned r2 = f2bf(b.x) | ((unsigned)f2bf(b.y) << 16);
  unsigned r3 = f2bf(b.z) | ((unsigned)f2bf(b.w) << 16);
  ((uint4*)xb)[blockIdx.x * 256 + tid] = make_uint4(r0, r1, r2, r3);

  float xa[8] = {a.x, a.y, a.z, a.w, b.x, b.y, b.z, b.w};
  int d0 = (tid & 127) * 8;
  const float* wbase = Wg + (size_t)d0 * EE;
  float acc[EE];
#pragma unroll
  for (int e = 0; e < EE; ++e) acc[e] = 0.f;
#pragma unroll
  for (int i = 0; i < 8; ++i) {
    float4 w0 = *(const float4*)(wbase + i * EE);
    float4 w1 = *(const float4*)(wbase + i * EE + 4);
    acc[0] += xa[i] * w0.x; acc[1] += xa[i] * w0.y;
    acc[2] += xa[i] * w0.z; acc[3] += xa[i] * w0.w;
    acc[4] += xa[i] * w1.x; acc[5] += xa[i] * w1.y;
    acc[6] += xa[i] * w1.z; acc[7] += xa[i] * w1.w;
  }
#pragma unroll
  for (int e = 0; e < EE; ++e) {
#pragma unroll
    for (int off = 32; off > 0; off >>= 1) acc[e] += __shfl_xor(acc[e], off);
  }
  __shared__ float rs[4][EE];
  int wv = tid >> 6;
  if ((tid & 63) == 0) {
#pragma unroll
    for (int e = 0; e < EE; ++e) rs[wv][e] = acc[e];
  }
  __syncthreads();
  if ((tid & 127) == 0) {
    int half = tid >> 7;
    int t = blockIdx.x * 2 + half;
    float v[EE];
#pragma unroll
    for (int e = 0; e < EE; ++e) v[e] = rs[2 * half][e] + rs[2 * half + 1][e] + bg[e];
    int i0 = 0;
#pragma unroll
    for (int e = 1; e < EE; ++e) if (v[e] > v[i0]) i0 = e;      // ties -> lowest idx
    int i1 = (i0 == 0) ? 1 : 0;
#pragma unroll
    for (int e = 0; e < EE; ++e) if (e != i0 && v[e] > v[i1]) i1 = e;
    float w1e = __expf(v[i1] - v[i0]);
    float inv = 1.f / (1.f + w1e);
    pair_e[2 * t] = i0;     pair_w[2 * t] = inv;
    pair_e[2 * t + 1] = i1; pair_w[2 * t + 1] = w1e * inv;
  }
}

// ------- LDS-aggregated histogram -------
__global__ __launch_bounds__(256) void count_kernel(const int* __restrict__ pair_e,
                                                    int* __restrict__ counts) {
  __shared__ int lh[EE];
  int tid = threadIdx.x;
  if (tid < EE) lh[tid] = 0;
  __syncthreads();
  int p = blockIdx.x * 256 + tid;
  atomicAdd(&lh[pair_e[p]], 1);
  __syncthreads();
  if (tid < EE) atomicAdd(&counts[tid], lh[tid]);
}

__global__ void prefix_kernel(const int* __restrict__ counts, int* __restrict__ offs,
                              int* __restrict__ cursor) {
  if (threadIdx.x == 0) {
    int s = 0;
    for (int e = 0; e < EE; ++e) { offs[e] = s; cursor[e] = s; s += counts[e]; }
    offs[EE] = s;
  }
}

// ------- chunk-reserving scatter -------
__global__ __launch_bounds__(256) void scatter_kernel(const int* __restrict__ pair_e,
                                                      int* __restrict__ cursor,
                                                      int* __restrict__ pair_rows) {
  __shared__ int lh[EE];
  __shared__ int lb[EE];
  int tid = threadIdx.x;
  if (tid < EE) lh[tid] = 0;
  __syncthreads();
  int p = blockIdx.x * 256 + tid;
  int e = pair_e[p];
  int r = atomicAdd(&lh[e], 1);
  __syncthreads();
  if (tid < EE) lb[tid] = atomicAdd(&cursor[tid], lh[tid]);
  __syncthreads();
  pair_rows[lb[e] + r] = p;
}

// ---- merged W1+W2 transpose+cvt, 64x64 tiles, float4 loads / ushort4 stores ----
__global__ __launch_bounds__(256) void transpose_cvt_kernel(
    const float* __restrict__ w1, unsigned short* __restrict__ o1,
    const float* __restrict__ w2, unsigned short* __restrict__ o2) {
  __shared__ float tile[64][65];
  int bid = blockIdx.x;
  int half = bid >> 12;                 // 0: W1, 1: W2
  int e = (bid >> 9) & 7;
  int tl = bid & 511;
  int R, C, tx, ty;
  const float* src;
  unsigned short* dst;
  if (half == 0) {
    R = DD; C = HHH; tx = tl & 31; ty = tl >> 5;      // 32 x 16
    src = w1 + (size_t)e * R * C; dst = o1 + (size_t)e * R * C;
  } else {
    R = HHH; C = DD; tx = tl & 15; ty = tl >> 4;      // 16 x 32
    src = w2 + (size_t)e * R * C; dst = o2 + (size_t)e * R * C;
  }
  int c0 = tx * 64, r0 = ty * 64;
  int t = threadIdx.x;
  int q = t & 15, r = t >> 4;
#pragma unroll
  for (int i = 0; i < 4; ++i) {
    int rr = r + 16 * i;
    float4 v = *(const float4*)(src + (size_t)(r0 + rr) * C + c0 + q * 4);
    tile[rr][q * 4 + 0] = v.x; tile[rr][q * 4 + 1] = v.y;
    tile[rr][q * 4 + 2] = v.z; tile[rr][q * 4 + 3] = v.w;
  }
  __syncthreads();
  int g = t & 15, cc = t >> 4;
#pragma unroll
  for (int i = 0; i < 4; ++i) {
    int c = cc + 16 * i;
    ushort4 o;
    o.x = f2bf(tile[g * 4 + 0][c]);
    o.y = f2bf(tile[g * 4 + 1][c]);
    o.z = f2bf(tile[g * 4 + 2][c]);
    o.w = f2bf(tile[g * 4 + 3][c]);
    *(ushort4*)(dst + (size_t)(c0 + c) * R + r0 + g * 4) = o;
  }
}

// --- grouped GEMM, 128x128 tile, BK=32, 3-slab ring, PAIR-structured (session best) ---
// Per pair P (tiles kt=2P, kt+1): vmcnt(0) -> barrier A -> read+MFMA tile kt (slab s0)
// -> barrier B -> sched_barrier -> batched stage tiles kt+2 (slab tg0=(s0+2)%3) and
// kt+3 (slab s0) [in readB's MFMA shadow] -> read+MFMA tile kt+1 (slab sB, no sync).
// Hazards: stage targets s0 (read before barrier B this pair) and tg0 (= prev pair's
// sB, read two barriers ago); readB's slab staged last pair, covered by this pair's
// vmcnt(0); overwrites of sB come after next barrier B.
// Grid-stride m-tiles (32 slots); expert->XCD pinning (d&7).
// MODE 0: A = xb gathered via pair_rows, epilogue relu -> h[sorted_pos]
// MODE 1: A = h (sorted rows direct),    epilogue gate-scale -> pairout[pair]
template <int MODE>
__global__ __launch_bounds__(256, 3) void moe_gemm_kernel(
    const unsigned short* __restrict__ Amat, const unsigned short* __restrict__ Bmat,
    const float* __restrict__ bias, const int* __restrict__ offsets,
    const int* __restrict__ pair_rows, const float* __restrict__ pair_w,
    unsigned short* __restrict__ Out, int Kd, int Nd, int nxlog) {
  int d = blockIdx.x;
  int e = d & 7;                               // expert == XCD (round-robin %8)
  int lin = d >> 3;
  int mt0 = lin >> nxlog;                      // starting m-tile slot [0,32)
  int n0 = (lin & ((1 << nxlog) - 1)) << 7;    // n-tile * 128
  int off = offsets[e];
  int cnt = offsets[e + 1] - off;
  int tid = threadIdx.x;
  int lane = tid & 63, wid = tid >> 6;

  __shared__ unsigned short As[3][128 * 32];   // 3 x 8 KB
  __shared__ unsigned short Bs[3][128 * 32];   // 3 x 8 KB  (48 KB total -> 3 blocks/CU)

  const unsigned short* Bex = Bmat + (size_t)e * Nd * Kd;
  int csw = (((tid & 3) ^ ((tid >> 2) & 3)) * 8);
  int wm = (wid >> 1) * 64, wn = (wid & 1) * 64;
  int lr = lane & 15;
  int t4 = lane >> 4;
  int lka = ((t4 ^ (lr & 3)) * 8);
  int NT = Kd >> 5;                            // even (32 or 64)

  for (int mt = mt0; mt * 128 < cnt; mt += 32) {
    __syncthreads();                          // prior mt's slot readers done

    const unsigned short* aptr[2];
    const unsigned short* bptr[2];
#pragma unroll
    for (int P = 0; P < 2; ++P) {
      int row = P * 64 + (tid >> 2);
      int sa = mt * 128 + row;
      if (sa >= cnt) sa = cnt - 1;            // clamp (dup loads; masked at C-write)
      int gr = (MODE == 0) ? (pair_rows[off + sa] >> 1) : (off + sa);
      aptr[P] = Amat + (size_t)gr * Kd + csw;
      bptr[P] = Bex + (size_t)(n0 + row) * Kd + csw;
    }

    floatx4 acc[4][4];
#pragma unroll
    for (int m = 0; m < 4; ++m)
#pragma unroll
      for (int n = 0; n < 4; ++n) acc[m][n] = (floatx4){0.f, 0.f, 0.f, 0.f};

    // prologue: stage K-tiles 0 and 1 into ring slots 0,1
#pragma unroll
    for (int P = 0; P < 2; ++P) {
      load_lds16(aptr[P], &As[0][P * 2048] + tid * 8);
      load_lds16(bptr[P], &Bs[0][P * 2048] + tid * 8);
    }
#pragma unroll
    for (int P = 0; P < 2; ++P) {
      load_lds16(aptr[P] + 32, &As[1][P * 2048] + tid * 8);
      load_lds16(bptr[P] + 32, &Bs[1][P * 2048] + tid * 8);
    }

    int s0 = 0;                               // slab of even tile of the pair
    int NP = NT >> 1;
    for (int P = 0; P < NP; ++P) {
      int kt = 2 * P;
      int sB = s0 + 1; if (sB == 3) sB = 0;
      int tg0 = s0 + 2; if (tg0 >= 3) tg0 -= 3;
      asm volatile("s_waitcnt vmcnt(0)" ::: "memory");  // tiles kt,kt+1 landed
      __builtin_amdgcn_s_barrier();                     // barrier A
      {
        bf16x8 af[4], bfr[4];
#pragma unroll
        for (int m = 0; m < 4; ++m)
          af[m] = *(const bf16x8*)(&As[s0][(wm + m * 16 + lr) * 32 + lka]);
#pragma unroll
        for (int n = 0; n < 4; ++n)
          bfr[n] = *(const bf16x8*)(&Bs[s0][(wn + n * 16 + lr) * 32 + lka]);
#pragma unroll
        for (int m = 0; m < 4; ++m)
#pragma unroll
          for (int n = 0; n < 4; ++n)
            acc[m][n] = __builtin_amdgcn_mfma_f32_16x16x32_bf16(af[m], bfr[n], acc[m][n], 0, 0, 0);
      }
      __builtin_amdgcn_s_barrier();                     // barrier B: slab reads done
      __builtin_amdgcn_sched_barrier(0);                // pin stages below barrier B
      if (kt + 2 < NT) {                                // stage tiles kt+2, kt+3
        int ko2 = (kt + 2) * 32, ko3 = (kt + 3) * 32;
#pragma unroll
        for (int Q = 0; Q < 2; ++Q) {
          load_lds16(aptr[Q] + ko2, &As[tg0][Q * 2048] + tid * 8);
          load_lds16(bptr[Q] + ko2, &Bs[tg0][Q * 2048] + tid * 8);
        }
#pragma unroll
        for (int Q = 0; Q < 2; ++Q) {
          load_lds16(aptr[Q] + ko3, &As[s0][Q * 2048] + tid * 8);
          load_lds16(bptr[Q] + ko3, &Bs[s0][Q * 2048] + tid * 8);
        }
      }
      {
        bf16x8 af[4], bfr[4];                           // tile kt+1: no sync prefix
#pragma unroll
        for (int m = 0; m < 4; ++m)
          af[m] = *(const bf16x8*)(&As[sB][(wm + m * 16 + lr) * 32 + lka]);
#pragma unroll
        for (int n = 0; n < 4; ++n)
          bfr[n] = *(const bf16x8*)(&Bs[sB][(wn + n * 16 + lr) * 32 + lka]);
#pragma unroll
        for (int m = 0; m < 4; ++m)
#pragma unroll
          for (int n = 0; n < 4; ++n)
            acc[m][n] = __builtin_amdgcn_mfma_f32_16x16x32_bf16(af[m], bfr[n], acc[m][n], 0, 0, 0);
      }
      s0 = tg0;                                         // (s0+2)%3
    }
    asm volatile("s_waitcnt vmcnt(0)" ::: "memory");    // clean load ledger for next mt

    int rem = cnt - mt * 128;
    if (rem > 128) rem = 128;
#pragma unroll
    for (int m = 0; m < 4; ++m) {
#pragma unroll
      for (int j = 0; j < 4; ++j) {
        int lrr = wm + m * 16 + ((lane >> 4) << 2) + j;   // C/D: col=lane&15, row=(lane>>4)*4+j
        if (lrr < rem) {
          int s = mt * 128 + lrr;
          size_t orow;
          float scale = 1.f;
          if (MODE == 0) {
            orow = (size_t)(off + s) * Nd;
          } else {
            int p = pair_rows[off + s];
            orow = (size_t)p * Nd;
            scale = pair_w[p];
          }
#pragma unroll
          for (int n = 0; n < 4; ++n) {
            int col = n0 + wn + n * 16 + lr;
            float v = acc[m][n][j] + bias[e * Nd + col];
            if (MODE == 0) v = fmaxf(v, 0.f);
            else v *= scale;
            Out[orow + col] = f2bf(v);
          }
        }
      }
    }
  }
}

// ---------------- fused epilogue: sum pairs, momentum, residual, LayerNorm ----------------
__global__ __launch_bounds__(256) void final_kernel(
    const float* __restrict__ x, const float* __restrict__ mom,
    const unsigned short* __restrict__ pairout, const float* __restrict__ ln_g,
    const float* __restrict__ ln_b, float* __restrict__ outp, float* __restrict__ nmp) {
  int t = blockIdx.x, tid = threadIdx.x;
  int d0 = tid * 4;
  size_t rowoff = (size_t)t * DD;
  const unsigned short* p0 = pairout + (size_t)(2 * t) * DD;
  const unsigned short* p1 = p0 + DD;
  float4 xv = *(const float4*)(x + rowoff + d0);
  float4 mv = *(const float4*)(mom + rowoff + d0);
  ushort4 u0 = *(const ushort4*)(p0 + d0);
  ushort4 u1 = *(const ushort4*)(p1 + d0);
  float eo[4] = {bf2f(u0.x) + bf2f(u1.x), bf2f(u0.y) + bf2f(u1.y),
                 bf2f(u0.z) + bf2f(u1.z), bf2f(u0.w) + bf2f(u1.w)};
  float xa[4] = {xv.x, xv.y, xv.z, xv.w};
  float ma[4] = {mv.x, mv.y, mv.z, mv.w};
  float o[4], nm[4];
  float s1 = 0.f, s2 = 0.f;
#pragma unroll
  for (int j = 0; j < 4; ++j) {
    nm[j] = MUf * ma[j] - eo[j];
    o[j] = xa[j] + GAMMAf * nm[j];
    s1 += o[j];
    s2 += o[j] * o[j];
  }
  *(float4*)(nmp + rowoff + d0) = make_float4(nm[0], nm[1], nm[2], nm[3]);
#pragma unroll
  for (int off = 32; off > 0; off >>= 1) {
    s1 += __shfl_xor(s1, off);
    s2 += __shfl_xor(s2, off);
  }
  __shared__ float rs[8];
  int wid = tid >> 6, lane = tid & 63;
  if (lane == 0) { rs[wid] = s1; rs[4 + wid] = s2; }
  __syncthreads();
  s1 = rs[0] + rs[1] + rs[2] + rs[3];
  s2 = rs[4] + rs[5] + rs[6] + rs[7];
  float mean = s1 * (1.f / DD);
  float var = s2 * (1.f / DD) - mean * mean;
  float rstd = rsqrtf(var + LNEPS);
  float4 g = *(const float4*)(ln_g + d0);
  float4 bb = *(const float4*)(ln_b + d0);
  float ga[4] = {g.x, g.y, g.z, g.w}, ba[4] = {bb.x, bb.y, bb.z, bb.w};
  float res[4];
#pragma unroll
  for (int j = 0; j < 4; ++j) res[j] = (o[j] - mean) * rstd * ga[j] + ba[j];
  *(float4*)(outp + rowoff + d0) = make_float4(res[0], res[1], res[2], res[3]);
}

extern "C" void kernel_launch(void* const* d_in, const int* in_sizes, int n_in,
                              void* d_out, int out_size, void* d_ws, size_t ws_size,
                              hipStream_t stream) {
  const float* x   = (const float*)d_in[0];
  const float* mom = (const float*)d_in[1];
  const float* Wg  = (const float*)d_in[2];
  const float* bg  = (const float*)d_in[3];
  const float* W1  = (const float*)d_in[4];
  const float* b1  = (const float*)d_in[5];
  const float* W2  = (const float*)d_in[6];
  const float* b2  = (const float*)d_in[7];
  const float* lng = (const float*)d_in[8];
  const float* lnb = (const float*)d_in[9];
  (void)in_sizes; (void)n_in; (void)out_size; (void)ws_size;
  float* outp = (float*)d_out;
  float* nmp  = outp + (size_t)TT * DD;

  char* base = (char*)d_ws;
  size_t off = 0;
  auto carve = [&](size_t bytes) {
    void* p = base + off;
    off += (bytes + 255) & ~(size_t)255;
    return p;
  };
  unsigned short* xb   = (unsigned short*)carve((size_t)TT * DD * 2);        // 16 MB
  unsigned short* w1t  = (unsigned short*)carve((size_t)EE * HHH * DD * 2);  // 32 MB  [E][H][D]
  unsigned short* w2t  = (unsigned short*)carve((size_t)EE * DD * HHH * 2);  // 32 MB  [E][D][H]
  unsigned short* hbuf = (unsigned short*)carve((size_t)2 * TT * HHH * 2);   // 64 MB
  unsigned short* pout = (unsigned short*)carve((size_t)2 * TT * DD * 2);    // 32 MB
  int*   pair_e    = (int*)carve((size_t)2 * TT * 4);
  float* pair_w    = (float*)carve((size_t)2 * TT * 4);
  int*   pair_rows = (int*)carve((size_t)2 * TT * 4);
  int*   counts    = (int*)carve(256);
  int*   offs      = (int*)carve(256);
  int*   cursor    = (int*)carve(256);

  hipMemsetAsync(counts, 0, EE * sizeof(int), stream);
  cvt_router_kernel<<<TT / 2, 256, 0, stream>>>(x, Wg, bg, xb, pair_e, pair_w);
  count_kernel<<<(2 * TT) / 256, 256, 0, stream>>>(pair_e, counts);
  prefix_kernel<<<1, 64, 0, stream>>>(counts, offs, cursor);
  scatter_kernel<<<(2 * TT) / 256, 256, 0, stream>>>(pair_e, cursor, pair_rows);
  transpose_cvt_kernel<<<8192, 256, 0, stream>>>(W1, w1t, W2, w2t);
  // flat grids: expert = blockIdx.x & 7; NX n-tiles x 32 m-tile start slots (grid-stride)
  moe_gemm_kernel<0><<<EE * (HHH / 128) * 32, 256, 0, stream>>>(
      xb, w1t, b1, offs, pair_rows, pair_w, hbuf, DD, HHH, 4);
  moe_gemm_kernel<1><<<EE * (DD / 128) * 32, 256, 0, stream>>>(
      hbuf, w2t, b2, offs, pair_rows, pair_w, pout, HHH, DD, 3);
  final_kernel<<<TT, 256, 0, stream>>>(x, mom, pout, lng, lnb, outp, nmp);
}

// Round 29
// 293.628 us; speedup vs baseline: 1.0378x; 1.0231x over previous
//
#include <hip/hip_runtime.h>

#define TT 8192          // B*S tokens
#define DD 1024          // model dim
#define HHH 2048         // hidden dim
#define EE 8             // experts
#define MUf 0.7f
#define GAMMAf 1.0f
#define LNEPS 1e-5f

typedef __bf16 bf16x8 __attribute__((ext_vector_type(8)));
typedef float floatx4 __attribute__((ext_vector_type(4)));

__device__ __forceinline__ unsigned short f2bf(float f) {
  unsigned u = __float_as_uint(f);
  u += 0x7FFFu + ((u >> 16) & 1u);          // round-to-nearest-even
  return (unsigned short)(u >> 16);
}
__device__ __forceinline__ float bf2f(unsigned short u) {
  return __uint_as_float(((unsigned)u) << 16);
}
__device__ __forceinline__ void load_lds16(const void* g, void* l) {
  __builtin_amdgcn_global_load_lds(
      (__attribute__((address_space(1))) void*)g,
      (__attribute__((address_space(3))) void*)l,
      16, 0, 0);
}

// ==== merged prep kernel: blocks 0..4095 = cvt+router; 4096..12287 = W transpose ====
// The two halves are data-independent; merging lets them co-run (both memory-bound,
// neither alone saturates 256 CUs at full BW) and removes one launch gap.
// Shared buffer sized for the transpose tile (64x65 f32); router path uses first 32.
__global__ __launch_bounds__(256) void prep_kernel(
    const float* __restrict__ x, const float* __restrict__ Wg, const float* __restrict__ bg,
    unsigned short* __restrict__ xb,
    int* __restrict__ pair_e, float* __restrict__ pair_w,
    const float* __restrict__ w1, unsigned short* __restrict__ o1,
    const float* __restrict__ w2, unsigned short* __restrict__ o2) {
  __shared__ float shbuf[64 * 65];
  int tid = threadIdx.x;
  int blk = blockIdx.x;

  if (blk < TT / 2) {
    // ---- cvt + router body (block = 2 token rows) ----
    size_t gi = (size_t)blk * 2048 + (size_t)tid * 8;
    const float4* s = (const float4*)(x + gi);
    float4 a = s[0], b = s[1];
    unsigned r0 = f2bf(a.x) | ((unsigned)f2bf(a.y) << 16);
    unsigned r1 = f2bf(a.z) | ((unsigned)f2bf(a.w) << 16);
    unsigned r2 = f2bf(b.x) | ((unsigned)f2bf(b.y) << 16);
    unsigned r3 = f2bf(b.z) | ((unsigned)f2bf(b.w) << 16);
    ((uint4*)xb)[blk * 256 + tid] = make_uint4(r0, r1, r2, r3);

    float xa[8] = {a.x, a.y, a.z, a.w, b.x, b.y, b.z, b.w};
    int d0 = (tid & 127) * 8;
    const float* wbase = Wg + (size_t)d0 * EE;
    float acc[EE];
#pragma unroll
    for (int e = 0; e < EE; ++e) acc[e] = 0.f;
#pragma unroll
    for (int i = 0; i < 8; ++i) {
      float4 w0 = *(const float4*)(wbase + i * EE);
      float4 w1v = *(const float4*)(wbase + i * EE + 4);
      acc[0] += xa[i] * w0.x; acc[1] += xa[i] * w0.y;
      acc[2] += xa[i] * w0.z; acc[3] += xa[i] * w0.w;
      acc[4] += xa[i] * w1v.x; acc[5] += xa[i] * w1v.y;
      acc[6] += xa[i] * w1v.z; acc[7] += xa[i] * w1v.w;
    }
#pragma unroll
    for (int e = 0; e < EE; ++e) {
#pragma unroll
      for (int off = 32; off > 0; off >>= 1) acc[e] += __shfl_xor(acc[e], off);
    }
    float (*rs)[EE] = (float (*)[EE])shbuf;   // rs[4][8]
    int wv = tid >> 6;
    if ((tid & 63) == 0) {
#pragma unroll
      for (int e = 0; e < EE; ++e) rs[wv][e] = acc[e];
    }
    __syncthreads();
    if ((tid & 127) == 0) {
      int half = tid >> 7;
      int t = blk * 2 + half;
      float v[EE];
#pragma unroll
      for (int e = 0; e < EE; ++e) v[e] = rs[2 * half][e] + rs[2 * half + 1][e] + bg[e];
      int i0 = 0;
#pragma unroll
      for (int e = 1; e < EE; ++e) if (v[e] > v[i0]) i0 = e;    // ties -> lowest idx
      int i1 = (i0 == 0) ? 1 : 0;
#pragma unroll
      for (int e = 0; e < EE; ++e) if (e != i0 && v[e] > v[i1]) i1 = e;
      float w1e = __expf(v[i1] - v[i0]);
      float inv = 1.f / (1.f + w1e);
      pair_e[2 * t] = i0;     pair_w[2 * t] = inv;
      pair_e[2 * t + 1] = i1; pair_w[2 * t + 1] = w1e * inv;
    }
  } else {
    // ---- W1/W2 transpose+cvt body (64x64 tile) ----
    int bid = blk - TT / 2;
    int half = bid >> 12;               // 0: W1, 1: W2
    int e = (bid >> 9) & 7;
    int tl = bid & 511;
    int R, C, tx, ty;
    const float* src;
    unsigned short* dst;
    if (half == 0) {
      R = DD; C = HHH; tx = tl & 31; ty = tl >> 5;    // 32 x 16
      src = w1 + (size_t)e * R * C; dst = o1 + (size_t)e * R * C;
    } else {
      R = HHH; C = DD; tx = tl & 15; ty = tl >> 4;    // 16 x 32
      src = w2 + (size_t)e * R * C; dst = o2 + (size_t)e * R * C;
    }
    float (*tile)[65] = (float (*)[65])shbuf;
    int c0 = tx * 64, r0 = ty * 64;
    int q = tid & 15, r = tid >> 4;
#pragma unroll
    for (int i = 0; i < 4; ++i) {
      int rr = r + 16 * i;
      float4 v = *(const float4*)(src + (size_t)(r0 + rr) * C + c0 + q * 4);
      tile[rr][q * 4 + 0] = v.x; tile[rr][q * 4 + 1] = v.y;
      tile[rr][q * 4 + 2] = v.z; tile[rr][q * 4 + 3] = v.w;
    }
    __syncthreads();
    int g = tid & 15, cc = tid >> 4;
#pragma unroll
    for (int i = 0; i < 4; ++i) {
      int c = cc + 16 * i;
      ushort4 o;
      o.x = f2bf(tile[g * 4 + 0][c]);
      o.y = f2bf(tile[g * 4 + 1][c]);
      o.z = f2bf(tile[g * 4 + 2][c]);
      o.w = f2bf(tile[g * 4 + 3][c]);
      *(ushort4*)(dst + (size_t)(c0 + c) * R + r0 + g * 4) = o;
    }
  }
}

// ------- LDS-aggregated histogram -------
__global__ __launch_bounds__(256) void count_kernel(const int* __restrict__ pair_e,
                                                    int* __restrict__ counts) {
  __shared__ int lh[EE];
  int tid = threadIdx.x;
  if (tid < EE) lh[tid] = 0;
  __syncthreads();
  int p = blockIdx.x * 256 + tid;
  atomicAdd(&lh[pair_e[p]], 1);
  __syncthreads();
  if (tid < EE) atomicAdd(&counts[tid], lh[tid]);
}

__global__ void prefix_kernel(const int* __restrict__ counts, int* __restrict__ offs,
                              int* __restrict__ cursor) {
  if (threadIdx.x == 0) {
    int s = 0;
    for (int e = 0; e < EE; ++e) { offs[e] = s; cursor[e] = s; s += counts[e]; }
    offs[EE] = s;
  }
}

// ------- chunk-reserving scatter -------
__global__ __launch_bounds__(256) void scatter_kernel(const int* __restrict__ pair_e,
                                                      int* __restrict__ cursor,
                                                      int* __restrict__ pair_rows) {
  __shared__ int lh[EE];
  __shared__ int lb[EE];
  int tid = threadIdx.x;
  if (tid < EE) lh[tid] = 0;
  __syncthreads();
  int p = blockIdx.x * 256 + tid;
  int e = pair_e[p];
  int r = atomicAdd(&lh[e], 1);
  __syncthreads();
  if (tid < EE) lb[tid] = atomicAdd(&cursor[tid], lh[tid]);
  __syncthreads();
  pair_rows[lb[e] + r] = p;
}

// --- grouped GEMM, 128x128 tile, BK=32, 3-slab ring, PAIR-structured (session best) ---
// Per pair P (tiles kt=2P, kt+1): vmcnt(0) -> barrier A -> read+MFMA tile kt (slab s0)
// -> barrier B -> sched_barrier -> batched stage tiles kt+2 (slab tg0=(s0+2)%3) and
// kt+3 (slab s0) [in readB's MFMA shadow] -> read+MFMA tile kt+1 (slab sB, no sync).
// Hazards: stage targets s0 (read before barrier B this pair) and tg0 (= prev pair's
// sB, read two barriers ago); readB's slab staged last pair, covered by this pair's
// vmcnt(0); overwrites of sB come after next barrier B.
// Grid-stride m-tiles (32 slots); expert->XCD pinning (d&7).
// MODE 0: A = xb gathered via pair_rows, epilogue relu -> h[sorted_pos]
// MODE 1: A = h (sorted rows direct),    epilogue gate-scale -> pairout[pair]
template <int MODE>
__global__ __launch_bounds__(256, 3) void moe_gemm_kernel(
    const unsigned short* __restrict__ Amat, const unsigned short* __restrict__ Bmat,
    const float* __restrict__ bias, const int* __restrict__ offsets,
    const int* __restrict__ pair_rows, const float* __restrict__ pair_w,
    unsigned short* __restrict__ Out, int Kd, int Nd, int nxlog) {
  int d = blockIdx.x;
  int e = d & 7;                               // expert == XCD (round-robin %8)
  int lin = d >> 3;
  int mt0 = lin >> nxlog;                      // starting m-tile slot [0,32)
  int n0 = (lin & ((1 << nxlog) - 1)) << 7;    // n-tile * 128
  int off = offsets[e];
  int cnt = offsets[e + 1] - off;
  int tid = threadIdx.x;
  int lane = tid & 63, wid = tid >> 6;

  __shared__ unsigned short As[3][128 * 32];   // 3 x 8 KB
  __shared__ unsigned short Bs[3][128 * 32];   // 3 x 8 KB  (48 KB total -> 3 blocks/CU)

  const unsigned short* Bex = Bmat + (size_t)e * Nd * Kd;
  int csw = (((tid & 3) ^ ((tid >> 2) & 3)) * 8);
  int wm = (wid >> 1) * 64, wn = (wid & 1) * 64;
  int lr = lane & 15;
  int t4 = lane >> 4;
  int lka = ((t4 ^ (lr & 3)) * 8);
  int NT = Kd >> 5;                            // even (32 or 64)

  for (int mt = mt0; mt * 128 < cnt; mt += 32) {
    __syncthreads();                          // prior mt's slot readers done

    const unsigned short* aptr[2];
    const unsigned short* bptr[2];
#pragma unroll
    for (int P = 0; P < 2; ++P) {
      int row = P * 64 + (tid >> 2);
      int sa = mt * 128 + row;
      if (sa >= cnt) sa = cnt - 1;            // clamp (dup loads; masked at C-write)
      int gr = (MODE == 0) ? (pair_rows[off + sa] >> 1) : (off + sa);
      aptr[P] = Amat + (size_t)gr * Kd + csw;
      bptr[P] = Bex + (size_t)(n0 + row) * Kd + csw;
    }

    floatx4 acc[4][4];
#pragma unroll
    for (int m = 0; m < 4; ++m)
#pragma unroll
      for (int n = 0; n < 4; ++n) acc[m][n] = (floatx4){0.f, 0.f, 0.f, 0.f};

    // prologue: stage K-tiles 0 and 1 into ring slots 0,1
#pragma unroll
    for (int P = 0; P < 2; ++P) {
      load_lds16(aptr[P], &As[0][P * 2048] + tid * 8);
      load_lds16(bptr[P], &Bs[0][P * 2048] + tid * 8);
    }
#pragma unroll
    for (int P = 0; P < 2; ++P) {
      load_lds16(aptr[P] + 32, &As[1][P * 2048] + tid * 8);
      load_lds16(bptr[P] + 32, &Bs[1][P * 2048] + tid * 8);
    }

    int s0 = 0;                               // slab of even tile of the pair
    int NP = NT >> 1;
    for (int P = 0; P < NP; ++P) {
      int kt = 2 * P;
      int sB = s0 + 1; if (sB == 3) sB = 0;
      int tg0 = s0 + 2; if (tg0 >= 3) tg0 -= 3;
      asm volatile("s_waitcnt vmcnt(0)" ::: "memory");  // tiles kt,kt+1 landed
      __builtin_amdgcn_s_barrier();                     // barrier A
      {
        bf16x8 af[4], bfr[4];
#pragma unroll
        for (int m = 0; m < 4; ++m)
          af[m] = *(const bf16x8*)(&As[s0][(wm + m * 16 + lr) * 32 + lka]);
#pragma unroll
        for (int n = 0; n < 4; ++n)
          bfr[n] = *(const bf16x8*)(&Bs[s0][(wn + n * 16 + lr) * 32 + lka]);
#pragma unroll
        for (int m = 0; m < 4; ++m)
#pragma unroll
          for (int n = 0; n < 4; ++n)
            acc[m][n] = __builtin_amdgcn_mfma_f32_16x16x32_bf16(af[m], bfr[n], acc[m][n], 0, 0, 0);
      }
      __builtin_amdgcn_s_barrier();                     // barrier B: slab reads done
      __builtin_amdgcn_sched_barrier(0);                // pin stages below barrier B
      if (kt + 2 < NT) {                                // stage tiles kt+2, kt+3
        int ko2 = (kt + 2) * 32, ko3 = (kt + 3) * 32;
#pragma unroll
        for (int Q = 0; Q < 2; ++Q) {
          load_lds16(aptr[Q] + ko2, &As[tg0][Q * 2048] + tid * 8);
          load_lds16(bptr[Q] + ko2, &Bs[tg0][Q * 2048] + tid * 8);
        }
#pragma unroll
        for (int Q = 0; Q < 2; ++Q) {
          load_lds16(aptr[Q] + ko3, &As[s0][Q * 2048] + tid * 8);
          load_lds16(bptr[Q] + ko3, &Bs[s0][Q * 2048] + tid * 8);
        }
      }
      {
        bf16x8 af[4], bfr[4];                           // tile kt+1: no sync prefix
#pragma unroll
        for (int m = 0; m < 4; ++m)
          af[m] = *(const bf16x8*)(&As[sB][(wm + m * 16 + lr) * 32 + lka]);
#pragma unroll
        for (int n = 0; n < 4; ++n)
          bfr[n] = *(const bf16x8*)(&Bs[sB][(wn + n * 16 + lr) * 32 + lka]);
#pragma unroll
        for (int m = 0; m < 4; ++m)
#pragma unroll
          for (int n = 0; n < 4; ++n)
            acc[m][n] = __builtin_amdgcn_mfma_f32_16x16x32_bf16(af[m], bfr[n], acc[m][n], 0, 0, 0);
      }
      s0 = tg0;                                         // (s0+2)%3
    }
    asm volatile("s_waitcnt vmcnt(0)" ::: "memory");    // clean load ledger for next mt

    int rem = cnt - mt * 128;
    if (rem > 128) rem = 128;
#pragma unroll
    for (int m = 0; m < 4; ++m) {
#pragma unroll
      for (int j = 0; j < 4; ++j) {
        int lrr = wm + m * 16 + ((lane >> 4) << 2) + j;   // C/D: col=lane&15, row=(lane>>4)*4+j
        if (lrr < rem) {
          int s = mt * 128 + lrr;
          size_t orow;
          float scale = 1.f;
          if (MODE == 0) {
            orow = (size_t)(off + s) * Nd;
          } else {
            int p = pair_rows[off + s];
            orow = (size_t)p * Nd;
            scale = pair_w[p];
          }
#pragma unroll
          for (int n = 0; n < 4; ++n) {
            int col = n0 + wn + n * 16 + lr;
            float v = acc[m][n][j] + bias[e * Nd + col];
            if (MODE == 0) v = fmaxf(v, 0.f);
            else v *= scale;
            Out[orow + col] = f2bf(v);
          }
        }
      }
    }
  }
}

// ---------------- fused epilogue: sum pairs, momentum, residual, LayerNorm ----------------
__global__ __launch_bounds__(256) void final_kernel(
    const float* __restrict__ x, const float* __restrict__ mom,
    const unsigned short* __restrict__ pairout, const float* __restrict__ ln_g,
    const float* __restrict__ ln_b, float* __restrict__ outp, float* __restrict__ nmp) {
  int t = blockIdx.x, tid = threadIdx.x;
  int d0 = tid * 4;
  size_t rowoff = (size_t)t * DD;
  const unsigned short* p0 = pairout + (size_t)(2 * t) * DD;
  const unsigned short* p1 = p0 + DD;
  float4 xv = *(const float4*)(x + rowoff + d0);
  float4 mv = *(const float4*)(mom + rowoff + d0);
  ushort4 u0 = *(const ushort4*)(p0 + d0);
  ushort4 u1 = *(const ushort4*)(p1 + d0);
  float eo[4] = {bf2f(u0.x) + bf2f(u1.x), bf2f(u0.y) + bf2f(u1.y),
                 bf2f(u0.z) + bf2f(u1.z), bf2f(u0.w) + bf2f(u1.w)};
  float xa[4] = {xv.x, xv.y, xv.z, xv.w};
  float ma[4] = {mv.x, mv.y, mv.z, mv.w};
  float o[4], nm[4];
  float s1 = 0.f, s2 = 0.f;
#pragma unroll
  for (int j = 0; j < 4; ++j) {
    nm[j] = MUf * ma[j] - eo[j];
    o[j] = xa[j] + GAMMAf * nm[j];
    s1 += o[j];
    s2 += o[j] * o[j];
  }
  *(float4*)(nmp + rowoff + d0) = make_float4(nm[0], nm[1], nm[2], nm[3]);
#pragma unroll
  for (int off = 32; off > 0; off >>= 1) {
    s1 += __shfl_xor(s1, off);
    s2 += __shfl_xor(s2, off);
  }
  __shared__ float rs[8];
  int wid = tid >> 6, lane = tid & 63;
  if (lane == 0) { rs[wid] = s1; rs[4 + wid] = s2; }
  __syncthreads();
  s1 = rs[0] + rs[1] + rs[2] + rs[3];
  s2 = rs[4] + rs[5] + rs[6] + rs[7];
  float mean = s1 * (1.f / DD);
  float var = s2 * (1.f / DD) - mean * mean;
  float rstd = rsqrtf(var + LNEPS);
  float4 g = *(const float4*)(ln_g + d0);
  float4 bb = *(const float4*)(ln_b + d0);
  float ga[4] = {g.x, g.y, g.z, g.w}, ba[4] = {bb.x, bb.y, bb.z, bb.w};
  float res[4];
#pragma unroll
  for (int j = 0; j < 4; ++j) res[j] = (o[j] - mean) * rstd * ga[j] + ba[j];
  *(float4*)(outp + rowoff + d0) = make_float4(res[0], res[1], res[2], res[3]);
}

extern "C" void kernel_launch(void* const* d_in, const int* in_sizes, int n_in,
                              void* d_out, int out_size, void* d_ws, size_t ws_size,
                              hipStream_t stream) {
  const float* x   = (const float*)d_in[0];
  const float* mom = (const float*)d_in[1];
  const float* Wg  = (const float*)d_in[2];
  const float* bg  = (const float*)d_in[3];
  const float* W1  = (const float*)d_in[4];
  const float* b1  = (const float*)d_in[5];
  const float* W2  = (const float*)d_in[6];
  const float* b2  = (const float*)d_in[7];
  const float* lng = (const float*)d_in[8];
  const float* lnb = (const float*)d_in[9];
  (void)in_sizes; (void)n_in; (void)out_size; (void)ws_size;
  float* outp = (float*)d_out;
  float* nmp  = outp + (size_t)TT * DD;

  char* base = (char*)d_ws;
  size_t off = 0;
  auto carve = [&](size_t bytes) {
    void* p = base + off;
    off += (bytes + 255) & ~(size_t)255;
    return p;
  };
  unsigned short* xb   = (unsigned short*)carve((size_t)TT * DD * 2);        // 16 MB
  unsigned short* w1t  = (unsigned short*)carve((size_t)EE * HHH * DD * 2);  // 32 MB  [E][H][D]
  unsigned short* w2t  = (unsigned short*)carve((size_t)EE * DD * HHH * 2);  // 32 MB  [E][D][H]
  unsigned short* hbuf = (unsigned short*)carve((size_t)2 * TT * HHH * 2);   // 64 MB
  unsigned short* pout = (unsigned short*)carve((size_t)2 * TT * DD * 2);    // 32 MB
  int*   pair_e    = (int*)carve((size_t)2 * TT * 4);
  float* pair_w    = (float*)carve((size_t)2 * TT * 4);
  int*   pair_rows = (int*)carve((size_t)2 * TT * 4);
  int*   counts    = (int*)carve(256);
  int*   offs      = (int*)carve(256);
  int*   cursor    = (int*)carve(256);

  hipMemsetAsync(counts, 0, EE * sizeof(int), stream);
  // merged cvt+router (blocks 0..4095) || W1/W2 transpose (blocks 4096..12287)
  prep_kernel<<<TT / 2 + 8192, 256, 0, stream>>>(x, Wg, bg, xb, pair_e, pair_w,
                                                 W1, w1t, W2, w2t);
  count_kernel<<<(2 * TT) / 256, 256, 0, stream>>>(pair_e, counts);
  prefix_kernel<<<1, 64, 0, stream>>>(counts, offs, cursor);
  scatter_kernel<<<(2 * TT) / 256, 256, 0, stream>>>(pair_e, cursor, pair_rows);
  // flat grids: expert = blockIdx.x & 7; NX n-tiles x 32 m-tile start slots (grid-stride)
  moe_gemm_kernel<0><<<EE * (HHH / 128) * 32, 256, 0, stream>>>(
      xb, w1t, b1, offs, pair_rows, pair_w, hbuf, DD, HHH, 4);
  moe_gemm_kernel<1><<<EE * (DD / 128) * 32, 256, 0, stream>>>(
      hbuf, w2t, b2, offs, pair_rows, pair_w, pout, HHH, DD, 3);
  final_kernel<<<TT, 256, 0, stream>>>(x, mom, pout, lng, lnb, outp, nmp);
}

// Round 30
// 293.205 us; speedup vs baseline: 1.0393x; 1.0014x over previous
//
#include <hip/hip_runtime.h>

#define TT 8192          // B*S tokens
#define DD 1024          // model dim
#define HHH 2048         // hidden dim
#define EE 8             // experts
#define MUf 0.7f
#define GAMMAf 1.0f
#define LNEPS 1e-5f

typedef __bf16 bf16x8 __attribute__((ext_vector_type(8)));
typedef float floatx4 __attribute__((ext_vector_type(4)));

__device__ __forceinline__ unsigned short f2bf(float f) {
  unsigned u = __float_as_uint(f);
  u += 0x7FFFu + ((u >> 16) & 1u);          // round-to-nearest-even
  return (unsigned short)(u >> 16);
}
__device__ __forceinline__ float bf2f(unsigned short u) {
  return __uint_as_float(((unsigned)u) << 16);
}
__device__ __forceinline__ void load_lds16(const void* g, void* l) {
  __builtin_amdgcn_global_load_lds(
      (__attribute__((address_space(1))) void*)g,
      (__attribute__((address_space(3))) void*)l,
      16, 0, 0);
}

// ==== merged prep kernel: blocks 0..4095 = cvt+router; 4096..12287 = W transpose ====
__global__ __launch_bounds__(256) void prep_kernel(
    const float* __restrict__ x, const float* __restrict__ Wg, const float* __restrict__ bg,
    unsigned short* __restrict__ xb,
    int* __restrict__ pair_e, float* __restrict__ pair_w,
    const float* __restrict__ w1, unsigned short* __restrict__ o1,
    const float* __restrict__ w2, unsigned short* __restrict__ o2) {
  __shared__ float shbuf[64 * 65];
  int tid = threadIdx.x;
  int blk = blockIdx.x;

  if (blk < TT / 2) {
    // ---- cvt + router body (block = 2 token rows) ----
    size_t gi = (size_t)blk * 2048 + (size_t)tid * 8;
    const float4* s = (const float4*)(x + gi);
    float4 a = s[0], b = s[1];
    unsigned r0 = f2bf(a.x) | ((unsigned)f2bf(a.y) << 16);
    unsigned r1 = f2bf(a.z) | ((unsigned)f2bf(a.w) << 16);
    unsigned r2 = f2bf(b.x) | ((unsigned)f2bf(b.y) << 16);
    unsigned r3 = f2bf(b.z) | ((unsigned)f2bf(b.w) << 16);
    ((uint4*)xb)[blk * 256 + tid] = make_uint4(r0, r1, r2, r3);

    float xa[8] = {a.x, a.y, a.z, a.w, b.x, b.y, b.z, b.w};
    int d0 = (tid & 127) * 8;
    const float* wbase = Wg + (size_t)d0 * EE;
    float acc[EE];
#pragma unroll
    for (int e = 0; e < EE; ++e) acc[e] = 0.f;
#pragma unroll
    for (int i = 0; i < 8; ++i) {
      float4 w0 = *(const float4*)(wbase + i * EE);
      float4 w1v = *(const float4*)(wbase + i * EE + 4);
      acc[0] += xa[i] * w0.x; acc[1] += xa[i] * w0.y;
      acc[2] += xa[i] * w0.z; acc[3] += xa[i] * w0.w;
      acc[4] += xa[i] * w1v.x; acc[5] += xa[i] * w1v.y;
      acc[6] += xa[i] * w1v.z; acc[7] += xa[i] * w1v.w;
    }
#pragma unroll
    for (int e = 0; e < EE; ++e) {
#pragma unroll
      for (int off = 32; off > 0; off >>= 1) acc[e] += __shfl_xor(acc[e], off);
    }
    float (*rs)[EE] = (float (*)[EE])shbuf;   // rs[4][8]
    int wv = tid >> 6;
    if ((tid & 63) == 0) {
#pragma unroll
      for (int e = 0; e < EE; ++e) rs[wv][e] = acc[e];
    }
    __syncthreads();
    if ((tid & 127) == 0) {
      int half = tid >> 7;
      int t = blk * 2 + half;
      float v[EE];
#pragma unroll
      for (int e = 0; e < EE; ++e) v[e] = rs[2 * half][e] + rs[2 * half + 1][e] + bg[e];
      int i0 = 0;
#pragma unroll
      for (int e = 1; e < EE; ++e) if (v[e] > v[i0]) i0 = e;    // ties -> lowest idx
      int i1 = (i0 == 0) ? 1 : 0;
#pragma unroll
      for (int e = 0; e < EE; ++e) if (e != i0 && v[e] > v[i1]) i1 = e;
      float w1e = __expf(v[i1] - v[i0]);
      float inv = 1.f / (1.f + w1e);
      pair_e[2 * t] = i0;     pair_w[2 * t] = inv;
      pair_e[2 * t + 1] = i1; pair_w[2 * t + 1] = w1e * inv;
    }
  } else {
    // ---- W1/W2 transpose+cvt body (64x64 tile) ----
    int bid = blk - TT / 2;
    int half = bid >> 12;               // 0: W1, 1: W2
    int e = (bid >> 9) & 7;
    int tl = bid & 511;
    int R, C, tx, ty;
    const float* src;
    unsigned short* dst;
    if (half == 0) {
      R = DD; C = HHH; tx = tl & 31; ty = tl >> 5;    // 32 x 16
      src = w1 + (size_t)e * R * C; dst = o1 + (size_t)e * R * C;
    } else {
      R = HHH; C = DD; tx = tl & 15; ty = tl >> 4;    // 16 x 32
      src = w2 + (size_t)e * R * C; dst = o2 + (size_t)e * R * C;
    }
    float (*tile)[65] = (float (*)[65])shbuf;
    int c0 = tx * 64, r0 = ty * 64;
    int q = tid & 15, r = tid >> 4;
#pragma unroll
    for (int i = 0; i < 4; ++i) {
      int rr = r + 16 * i;
      float4 v = *(const float4*)(src + (size_t)(r0 + rr) * C + c0 + q * 4);
      tile[rr][q * 4 + 0] = v.x; tile[rr][q * 4 + 1] = v.y;
      tile[rr][q * 4 + 2] = v.z; tile[rr][q * 4 + 3] = v.w;
    }
    __syncthreads();
    int g = tid & 15, cc = tid >> 4;
#pragma unroll
    for (int i = 0; i < 4; ++i) {
      int c = cc + 16 * i;
      ushort4 o;
      o.x = f2bf(tile[g * 4 + 0][c]);
      o.y = f2bf(tile[g * 4 + 1][c]);
      o.z = f2bf(tile[g * 4 + 2][c]);
      o.w = f2bf(tile[g * 4 + 3][c]);
      *(ushort4*)(dst + (size_t)(c0 + c) * R + r0 + g * 4) = o;
    }
  }
}

// ------- LDS-aggregated histogram -------
__global__ __launch_bounds__(256) void count_kernel(const int* __restrict__ pair_e,
                                                    int* __restrict__ counts) {
  __shared__ int lh[EE];
  int tid = threadIdx.x;
  if (tid < EE) lh[tid] = 0;
  __syncthreads();
  int p = blockIdx.x * 256 + tid;
  atomicAdd(&lh[pair_e[p]], 1);
  __syncthreads();
  if (tid < EE) atomicAdd(&counts[tid], lh[tid]);
}

// ------- scatter with inlined prefix (prefix_kernel launch removed) -------
// counts complete (prior dispatch). Each block: LDS histogram -> local exclusive prefix
// from counts (pure function of final counts) -> chunk reserve on zero-init cursor ->
// base = prefix + reserved. Block 0 also writes offs[] for the GEMMs (same values from
// every thread's view; ordered before GEMM launch by stream semantics).
__global__ __launch_bounds__(256) void scatter_kernel(const int* __restrict__ pair_e,
                                                      const int* __restrict__ counts,
                                                      int* __restrict__ cursor,
                                                      int* __restrict__ offs,
                                                      int* __restrict__ pair_rows) {
  __shared__ int lh[EE];
  __shared__ int lb[EE];
  int tid = threadIdx.x;
  if (tid < EE) lh[tid] = 0;
  __syncthreads();
  int p = blockIdx.x * 256 + tid;
  int e = pair_e[p];
  int r = atomicAdd(&lh[e], 1);
  __syncthreads();
  if (tid < EE) {
    int s = 0;
    for (int q = 0; q < tid; ++q) s += counts[q];   // exclusive prefix (tid<8, L2-hot)
    lb[tid] = s + atomicAdd(&cursor[tid], lh[tid]); // chunk base
    if (blockIdx.x == 0) {
      offs[tid] = s;
      if (tid == EE - 1) offs[EE] = s + counts[EE - 1];
    }
  }
  __syncthreads();
  pair_rows[lb[e] + r] = p;
}

// --- grouped GEMM, 128x128 tile, BK=32, 3-slab ring, PAIR-structured (session best) ---
// Per pair P (tiles kt=2P, kt+1): vmcnt(0) -> barrier A -> read+MFMA tile kt (slab s0)
// -> barrier B -> sched_barrier -> batched stage tiles kt+2 (slab tg0=(s0+2)%3) and
// kt+3 (slab s0) [in readB's MFMA shadow] -> read+MFMA tile kt+1 (slab sB, no sync).
// Hazards: stage targets s0 (read before barrier B this pair) and tg0 (= prev pair's
// sB, read two barriers ago); readB's slab staged last pair, covered by this pair's
// vmcnt(0); overwrites of sB come after next barrier B.
// Grid-stride m-tiles (32 slots); expert->XCD pinning (d&7).
// MODE 0: A = xb gathered via pair_rows, epilogue relu -> h[sorted_pos]
// MODE 1: A = h (sorted rows direct),    epilogue gate-scale -> pairout[pair]
template <int MODE>
__global__ __launch_bounds__(256, 3) void moe_gemm_kernel(
    const unsigned short* __restrict__ Amat, const unsigned short* __restrict__ Bmat,
    const float* __restrict__ bias, const int* __restrict__ offsets,
    const int* __restrict__ pair_rows, const float* __restrict__ pair_w,
    unsigned short* __restrict__ Out, int Kd, int Nd, int nxlog) {
  int d = blockIdx.x;
  int e = d & 7;                               // expert == XCD (round-robin %8)
  int lin = d >> 3;
  int mt0 = lin >> nxlog;                      // starting m-tile slot [0,32)
  int n0 = (lin & ((1 << nxlog) - 1)) << 7;    // n-tile * 128
  int off = offsets[e];
  int cnt = offsets[e + 1] - off;
  int tid = threadIdx.x;
  int lane = tid & 63, wid = tid >> 6;

  __shared__ unsigned short As[3][128 * 32];   // 3 x 8 KB
  __shared__ unsigned short Bs[3][128 * 32];   // 3 x 8 KB  (48 KB total -> 3 blocks/CU)

  const unsigned short* Bex = Bmat + (size_t)e * Nd * Kd;
  int csw = (((tid & 3) ^ ((tid >> 2) & 3)) * 8);
  int wm = (wid >> 1) * 64, wn = (wid & 1) * 64;
  int lr = lane & 15;
  int t4 = lane >> 4;
  int lka = ((t4 ^ (lr & 3)) * 8);
  int NT = Kd >> 5;                            // even (32 or 64)

  for (int mt = mt0; mt * 128 < cnt; mt += 32) {
    __syncthreads();                          // prior mt's slot readers done

    const unsigned short* aptr[2];
    const unsigned short* bptr[2];
#pragma unroll
    for (int P = 0; P < 2; ++P) {
      int row = P * 64 + (tid >> 2);
      int sa = mt * 128 + row;
      if (sa >= cnt) sa = cnt - 1;            // clamp (dup loads; masked at C-write)
      int gr = (MODE == 0) ? (pair_rows[off + sa] >> 1) : (off + sa);
      aptr[P] = Amat + (size_t)gr * Kd + csw;
      bptr[P] = Bex + (size_t)(n0 + row) * Kd + csw;
    }

    floatx4 acc[4][4];
#pragma unroll
    for (int m = 0; m < 4; ++m)
#pragma unroll
      for (int n = 0; n < 4; ++n) acc[m][n] = (floatx4){0.f, 0.f, 0.f, 0.f};

    // prologue: stage K-tiles 0 and 1 into ring slots 0,1
#pragma unroll
    for (int P = 0; P < 2; ++P) {
      load_lds16(aptr[P], &As[0][P * 2048] + tid * 8);
      load_lds16(bptr[P], &Bs[0][P * 2048] + tid * 8);
    }
#pragma unroll
    for (int P = 0; P < 2; ++P) {
      load_lds16(aptr[P] + 32, &As[1][P * 2048] + tid * 8);
      load_lds16(bptr[P] + 32, &Bs[1][P * 2048] + tid * 8);
    }

    int s0 = 0;                               // slab of even tile of the pair
    int NP = NT >> 1;
    for (int P = 0; P < NP; ++P) {
      int kt = 2 * P;
      int sB = s0 + 1; if (sB == 3) sB = 0;
      int tg0 = s0 + 2; if (tg0 >= 3) tg0 -= 3;
      asm volatile("s_waitcnt vmcnt(0)" ::: "memory");  // tiles kt,kt+1 landed
      __builtin_amdgcn_s_barrier();                     // barrier A
      {
        bf16x8 af[4], bfr[4];
#pragma unroll
        for (int m = 0; m < 4; ++m)
          af[m] = *(const bf16x8*)(&As[s0][(wm + m * 16 + lr) * 32 + lka]);
#pragma unroll
        for (int n = 0; n < 4; ++n)
          bfr[n] = *(const bf16x8*)(&Bs[s0][(wn + n * 16 + lr) * 32 + lka]);
#pragma unroll
        for (int m = 0; m < 4; ++m)
#pragma unroll
          for (int n = 0; n < 4; ++n)
            acc[m][n] = __builtin_amdgcn_mfma_f32_16x16x32_bf16(af[m], bfr[n], acc[m][n], 0, 0, 0);
      }
      __builtin_amdgcn_s_barrier();                     // barrier B: slab reads done
      __builtin_amdgcn_sched_barrier(0);                // pin stages below barrier B
      if (kt + 2 < NT) {                                // stage tiles kt+2, kt+3
        int ko2 = (kt + 2) * 32, ko3 = (kt + 3) * 32;
#pragma unroll
        for (int Q = 0; Q < 2; ++Q) {
          load_lds16(aptr[Q] + ko2, &As[tg0][Q * 2048] + tid * 8);
          load_lds16(bptr[Q] + ko2, &Bs[tg0][Q * 2048] + tid * 8);
        }
#pragma unroll
        for (int Q = 0; Q < 2; ++Q) {
          load_lds16(aptr[Q] + ko3, &As[s0][Q * 2048] + tid * 8);
          load_lds16(bptr[Q] + ko3, &Bs[s0][Q * 2048] + tid * 8);
        }
      }
      {
        bf16x8 af[4], bfr[4];                           // tile kt+1: no sync prefix
#pragma unroll
        for (int m = 0; m < 4; ++m)
          af[m] = *(const bf16x8*)(&As[sB][(wm + m * 16 + lr) * 32 + lka]);
#pragma unroll
        for (int n = 0; n < 4; ++n)
          bfr[n] = *(const bf16x8*)(&Bs[sB][(wn + n * 16 + lr) * 32 + lka]);
#pragma unroll
        for (int m = 0; m < 4; ++m)
#pragma unroll
          for (int n = 0; n < 4; ++n)
            acc[m][n] = __builtin_amdgcn_mfma_f32_16x16x32_bf16(af[m], bfr[n], acc[m][n], 0, 0, 0);
      }
      s0 = tg0;                                         // (s0+2)%3
    }
    asm volatile("s_waitcnt vmcnt(0)" ::: "memory");    // clean load ledger for next mt

    int rem = cnt - mt * 128;
    if (rem > 128) rem = 128;
#pragma unroll
    for (int m = 0; m < 4; ++m) {
#pragma unroll
      for (int j = 0; j < 4; ++j) {
        int lrr = wm + m * 16 + ((lane >> 4) << 2) + j;   // C/D: col=lane&15, row=(lane>>4)*4+j
        if (lrr < rem) {
          int s = mt * 128 + lrr;
          size_t orow;
          float scale = 1.f;
          if (MODE == 0) {
            orow = (size_t)(off + s) * Nd;
          } else {
            int p = pair_rows[off + s];
            orow = (size_t)p * Nd;
            scale = pair_w[p];
          }
#pragma unroll
          for (int n = 0; n < 4; ++n) {
            int col = n0 + wn + n * 16 + lr;
            float v = acc[m][n][j] + bias[e * Nd + col];
            if (MODE == 0) v = fmaxf(v, 0.f);
            else v *= scale;
            Out[orow + col] = f2bf(v);
          }
        }
      }
    }
  }
}

// ---------------- fused epilogue: sum pairs, momentum, residual, LayerNorm ----------------
__global__ __launch_bounds__(256) void final_kernel(
    const float* __restrict__ x, const float* __restrict__ mom,
    const unsigned short* __restrict__ pairout, const float* __restrict__ ln_g,
    const float* __restrict__ ln_b, float* __restrict__ outp, float* __restrict__ nmp) {
  int t = blockIdx.x, tid = threadIdx.x;
  int d0 = tid * 4;
  size_t rowoff = (size_t)t * DD;
  const unsigned short* p0 = pairout + (size_t)(2 * t) * DD;
  const unsigned short* p1 = p0 + DD;
  float4 xv = *(const float4*)(x + rowoff + d0);
  float4 mv = *(const float4*)(mom + rowoff + d0);
  ushort4 u0 = *(const ushort4*)(p0 + d0);
  ushort4 u1 = *(const ushort4*)(p1 + d0);
  float eo[4] = {bf2f(u0.x) + bf2f(u1.x), bf2f(u0.y) + bf2f(u1.y),
                 bf2f(u0.z) + bf2f(u1.z), bf2f(u0.w) + bf2f(u1.w)};
  float xa[4] = {xv.x, xv.y, xv.z, xv.w};
  float ma[4] = {mv.x, mv.y, mv.z, mv.w};
  float o[4], nm[4];
  float s1 = 0.f, s2 = 0.f;
#pragma unroll
  for (int j = 0; j < 4; ++j) {
    nm[j] = MUf * ma[j] - eo[j];
    o[j] = xa[j] + GAMMAf * nm[j];
    s1 += o[j];
    s2 += o[j] * o[j];
  }
  *(float4*)(nmp + rowoff + d0) = make_float4(nm[0], nm[1], nm[2], nm[3]);
#pragma unroll
  for (int off = 32; off > 0; off >>= 1) {
    s1 += __shfl_xor(s1, off);
    s2 += __shfl_xor(s2, off);
  }
  __shared__ float rs[8];
  int wid = tid >> 6, lane = tid & 63;
  if (lane == 0) { rs[wid] = s1; rs[4 + wid] = s2; }
  __syncthreads();
  s1 = rs[0] + rs[1] + rs[2] + rs[3];
  s2 = rs[4] + rs[5] + rs[6] + rs[7];
  float mean = s1 * (1.f / DD);
  float var = s2 * (1.f / DD) - mean * mean;
  float rstd = rsqrtf(var + LNEPS);
  float4 g = *(const float4*)(ln_g + d0);
  float4 bb = *(const float4*)(ln_b + d0);
  float ga[4] = {g.x, g.y, g.z, g.w}, ba[4] = {bb.x, bb.y, bb.z, bb.w};
  float res[4];
#pragma unroll
  for (int j = 0; j < 4; ++j) res[j] = (o[j] - mean) * rstd * ga[j] + ba[j];
  *(float4*)(outp + rowoff + d0) = make_float4(res[0], res[1], res[2], res[3]);
}

extern "C" void kernel_launch(void* const* d_in, const int* in_sizes, int n_in,
                              void* d_out, int out_size, void* d_ws, size_t ws_size,
                              hipStream_t stream) {
  const float* x   = (const float*)d_in[0];
  const float* mom = (const float*)d_in[1];
  const float* Wg  = (const float*)d_in[2];
  const float* bg  = (const float*)d_in[3];
  const float* W1  = (const float*)d_in[4];
  const float* b1  = (const float*)d_in[5];
  const float* W2  = (const float*)d_in[6];
  const float* b2  = (const float*)d_in[7];
  const float* lng = (const float*)d_in[8];
  const float* lnb = (const float*)d_in[9];
  (void)in_sizes; (void)n_in; (void)out_size; (void)ws_size;
  float* outp = (float*)d_out;
  float* nmp  = outp + (size_t)TT * DD;

  char* base = (char*)d_ws;
  size_t off = 0;
  auto carve = [&](size_t bytes) {
    void* p = base + off;
    off += (bytes + 255) & ~(size_t)255;
    return p;
  };
  unsigned short* xb   = (unsigned short*)carve((size_t)TT * DD * 2);        // 16 MB
  unsigned short* w1t  = (unsigned short*)carve((size_t)EE * HHH * DD * 2);  // 32 MB  [E][H][D]
  unsigned short* w2t  = (unsigned short*)carve((size_t)EE * DD * HHH * 2);  // 32 MB  [E][D][H]
  unsigned short* hbuf = (unsigned short*)carve((size_t)2 * TT * HHH * 2);   // 64 MB
  unsigned short* pout = (unsigned short*)carve((size_t)2 * TT * DD * 2);    // 32 MB
  int*   pair_e    = (int*)carve((size_t)2 * TT * 4);
  float* pair_w    = (float*)carve((size_t)2 * TT * 4);
  int*   pair_rows = (int*)carve((size_t)2 * TT * 4);
  int*   counts    = (int*)carve(256);       // counts, offs, cursor contiguous (768 B)
  int*   offs      = (int*)carve(256);
  int*   cursor    = (int*)carve(256);

  hipMemsetAsync(counts, 0, 768, stream);    // clears counts + offs + cursor
  // merged cvt+router (blocks 0..4095) || W1/W2 transpose (blocks 4096..12287)
  prep_kernel<<<TT / 2 + 8192, 256, 0, stream>>>(x, Wg, bg, xb, pair_e, pair_w,
                                                 W1, w1t, W2, w2t);
  count_kernel<<<(2 * TT) / 256, 256, 0, stream>>>(pair_e, counts);
  scatter_kernel<<<(2 * TT) / 256, 256, 0, stream>>>(pair_e, counts, cursor, offs, pair_rows);
  // flat grids: expert = blockIdx.x & 7; NX n-tiles x 32 m-tile start slots (grid-stride)
  moe_gemm_kernel<0><<<EE * (HHH / 128) * 32, 256, 0, stream>>>(
      xb, w1t, b1, offs, pair_rows, pair_w, hbuf, DD, HHH, 4);
  moe_gemm_kernel<1><<<EE * (DD / 128) * 32, 256, 0, stream>>>(
      hbuf, w2t, b2, offs, pair_rows, pair_w, pout, HHH, DD, 3);
  final_kernel<<<TT, 256, 0, stream>>>(x, mom, pout, lng, lnb, outp, nmp);
}